// Round 1
// baseline (869.159 us; speedup 1.0000x reference)
//
#include <hip/hip_runtime.h>
#include <hip/hip_bf16.h>

// Problem constants
#define B_SZ   64
#define L_SZ   52
#define DMODEL 4096
#define H_SZ   32
#define C_SZ   128   // NEW_C = DMODEL/H
#define DK     128   // D_K == D_V

// GEMM dims: (B*L) x DMODEL = 3328 x 4096, K = 4096
#define GM 3328
#define GN 4096
#define GK 4096

typedef __bf16 bf16x8 __attribute__((ext_vector_type(8)));
typedef float  f32x4  __attribute__((ext_vector_type(4)));
typedef unsigned short u16x8 __attribute__((ext_vector_type(8)));

__device__ __forceinline__ float b2f(unsigned short u) {
  union { unsigned int i; float f; } x;
  x.i = ((unsigned int)u) << 16;
  return x.f;
}

__device__ __forceinline__ void gload_lds16(const void* g, void* l) {
  __builtin_amdgcn_global_load_lds(
      (__attribute__((address_space(1))) void*)(void*)g,
      (__attribute__((address_space(3))) void*)l, 16, 0, 0);
}

// ---------------------------------------------------------------------------
// Kernel 1: Wo (4096x4096 fp32, row-major [m][n]) -> WoT (4096x4096 bf16, [n][m])
// ---------------------------------------------------------------------------
__global__ __launch_bounds__(256) void wo_transpose_kernel(
    const float* __restrict__ Wo, __hip_bfloat16* __restrict__ WoT) {
  __shared__ float tile[64][65];  // +1 pad: conflict-free transpose reads
  const int nt = blockIdx.x, mt = blockIdx.y;
  const int t = threadIdx.x;
  const int r  = t >> 4;          // 0..15
  const int c4 = (t & 15) << 2;   // 0,4,...,60
#pragma unroll
  for (int p = 0; p < 4; ++p) {
    const int rr = r + p * 16;
    const float4 v = *(const float4*)(Wo + (size_t)(mt * 64 + rr) * 4096 + nt * 64 + c4);
    tile[rr][c4 + 0] = v.x; tile[rr][c4 + 1] = v.y;
    tile[rr][c4 + 2] = v.z; tile[rr][c4 + 3] = v.w;
  }
  __syncthreads();
#pragma unroll
  for (int p = 0; p < 4; ++p) {
    const int rr = r + p * 16;  // local n index
    union { __hip_bfloat16 h[4]; ushort4 u; } o4;
#pragma unroll
    for (int e = 0; e < 4; ++e) o4.h[e] = __float2bfloat16(tile[c4 + e][rr]);
    *(ushort4*)(WoT + (size_t)(nt * 64 + rr) * 4096 + mt * 64 + c4) = o4.u;
  }
}

// ---------------------------------------------------------------------------
// Kernel 2: per-(b,h) QKV projection + causal attention.
// Block = 512 threads (8 waves). q/k/v stored bf16 in LDS with stride 136
// (row byte stride 272 = 16B aligned; bank index rotates by (row + col/2)%32
// -> conflict-free column access). Softmax is wave-parallel: lane = key index.
// Output o written bf16 into ws as row-major (B*L, H*DV).
// ---------------------------------------------------------------------------
#define QSTR 136

__device__ __forceinline__ void proj_one(const float* __restrict__ X,
                                         const float* __restrict__ W, float bias,
                                         __hip_bfloat16* __restrict__ sh,
                                         int kx, int lg) {
  float acc[13];
#pragma unroll
  for (int i = 0; i < 13; ++i) acc[i] = bias;
  for (int c = 0; c < 128; c += 4) {
    const float w0 = W[(c + 0) * 128 + kx];
    const float w1 = W[(c + 1) * 128 + kx];
    const float w2 = W[(c + 2) * 128 + kx];
    const float w3 = W[(c + 3) * 128 + kx];
#pragma unroll
    for (int i = 0; i < 13; ++i) {
      const float4 x4 = *(const float4*)(X + (lg + 4 * i) * 128 + c);
      acc[i] = fmaf(x4.x, w0, acc[i]);
      acc[i] = fmaf(x4.y, w1, acc[i]);
      acc[i] = fmaf(x4.z, w2, acc[i]);
      acc[i] = fmaf(x4.w, w3, acc[i]);
    }
  }
#pragma unroll
  for (int i = 0; i < 13; ++i)
    sh[(lg + 4 * i) * QSTR + kx] = __float2bfloat16(acc[i]);
}

__global__ __launch_bounds__(512, 2) void attn_kernel(
    const float* __restrict__ Qin, const float* __restrict__ Kin,
    const float* __restrict__ Vin,
    const float* __restrict__ Wq, const float* __restrict__ bq,
    const float* __restrict__ Wk, const float* __restrict__ bk,
    const float* __restrict__ Wv, const float* __restrict__ bv,
    __hip_bfloat16* __restrict__ Oc) {
  __shared__ __align__(16) __hip_bfloat16 q_sh[L_SZ * QSTR];
  __shared__ __align__(16) __hip_bfloat16 k_sh[L_SZ * QSTR];
  __shared__ __align__(16) __hip_bfloat16 v_sh[L_SZ * QSTR];
  __shared__ float s_sh[L_SZ * 56];   // attn probs, row stride 56

  const int h = blockIdx.x, b = blockIdx.y;
  const int t = threadIdx.x;
  const size_t xoff = (size_t)b * (L_SZ * DMODEL) + (size_t)h * (L_SZ * C_SZ);
  const int kx = t & 127, lg = t >> 7;      // lg uniform per wave
  const int wofs = h * (C_SZ * DK);

  // ---- phase 1: q/k/v projections (fp32 math, bf16 store to LDS) ----
  proj_one(Qin + xoff, Wq + wofs, bq[h * DK + kx], q_sh, kx, lg);
  proj_one(Kin + xoff, Wk + wofs, bk[h * DK + kx], k_sh, kx, lg);
  proj_one(Vin + xoff, Wv + wofs, bv[h * DK + kx], v_sh, kx, lg);
  __syncthreads();

  // ---- phase 2: scores + causal masked softmax (lane j = key index) ----
  {
    const int w = t >> 6, lane = t & 63;
    const int j = lane;
    const int jc = j < 51 ? j : 51;   // clamp OOB lanes (masked anyway)
    const float scale = 0.0883883476483184f;  // 1/sqrt(128)
    for (int i = w; i < 52; i += 8) {
      const u16x8* qr = (const u16x8*)(q_sh + i * QSTR);
      const u16x8* kr = (const u16x8*)(k_sh + jc * QSTR);
      float dot = 0.f;
#pragma unroll
      for (int cc = 0; cc < 16; ++cc) {
        const u16x8 qv = qr[cc], kv = kr[cc];
#pragma unroll
        for (int e = 0; e < 8; ++e) dot = fmaf(b2f(qv[e]), b2f(kv[e]), dot);
      }
      const bool valid = (j <= i);
      float sv = valid ? dot * scale : -1e30f;
      float mx = sv;
#pragma unroll
      for (int d = 1; d < 64; d <<= 1) mx = fmaxf(mx, __shfl_xor(mx, d));
      float ex = valid ? __expf(sv - mx) : 0.f;
      float sum = ex;
#pragma unroll
      for (int d = 1; d < 64; d <<= 1) sum += __shfl_xor(sum, d);
      if (j < 52) s_sh[i * 56 + j] = ex / sum;  // masked lanes store 0
    }
  }
  __syncthreads();

  // ---- phase 3: o = attn @ v ; write bf16 to (B*L, H*DV) ws ----
  {
    float oacc[13];
#pragma unroll
    for (int i = 0; i < 13; ++i) oacc[i] = 0.f;
    for (int jj = 0; jj < 52; ++jj) {
      const float vv = __bfloat162float(v_sh[jj * QSTR + kx]);
#pragma unroll
      for (int i = 0; i < 13; ++i)
        oacc[i] = fmaf(s_sh[(lg + 4 * i) * 56 + jj], vv, oacc[i]);
    }
    const size_t obase = ((size_t)b * L_SZ) * (size_t)DMODEL + (size_t)h * DK + kx;
#pragma unroll
    for (int i = 0; i < 13; ++i)
      Oc[obase + (size_t)(lg + 4 * i) * DMODEL] = __float2bfloat16(oacc[i]);
  }
}

// ---------------------------------------------------------------------------
// Kernel 3: C(3328x4096) = A(3328x4096 bf16) @ WoT(4096x4096 bf16, N-major)^T
//           + bias. m97-verified structure: 128x128 tile, BK=32, 4 waves,
//           global_load_lds width 16, mfma_f32_16x16x32_bf16.
// ---------------------------------------------------------------------------
__global__ __launch_bounds__(256, 2) void out_gemm_kernel(
    const __hip_bfloat16* __restrict__ A, const __hip_bfloat16* __restrict__ Bt,
    const float* __restrict__ bias, float* __restrict__ C) {
  __shared__ __align__(16) __hip_bfloat16 a_sh[128 * 32];
  __shared__ __align__(16) __hip_bfloat16 b_sh[128 * 32];

  // bijective XCD swizzle (832 % 8 == 0)
  int bid = blockIdx.x;
  bid = (bid & 7) * (26 * 32 / 8) + (bid >> 3);
  const int tm = bid >> 5;   // 0..25
  const int tn = bid & 31;   // 0..31

  const int t = threadIdx.x;
  const int lane = t & 63;
  const int w = t >> 6, wr = w >> 1, wc = w & 1;
  const int r16 = lane & 15, kq = lane >> 4;

  f32x4 acc[4][4] = {};

  // staging: thread t covers 16B chunk; row = t>>2 (+64 for 2nd call), k-off = (t&3)*8
  const __hip_bfloat16* ga = A  + (size_t)(tm * 128 + (t >> 2)) * GK + (t & 3) * 8;
  const __hip_bfloat16* gb = Bt + (size_t)(tn * 128 + (t >> 2)) * GK + (t & 3) * 8;
  char* la = (char*)a_sh + t * 16;
  char* lb = (char*)b_sh + t * 16;

  const int a_rd = (wr * 64 + r16) * 32 + kq * 8;  // element offsets
  const int b_rd = (wc * 64 + r16) * 32 + kq * 8;

  for (int k0 = 0; k0 < GK; k0 += 32) {
    gload_lds16(ga + k0,                     la);
    gload_lds16(ga + (size_t)64 * GK + k0,   la + 4096);
    gload_lds16(gb + k0,                     lb);
    gload_lds16(gb + (size_t)64 * GK + k0,   lb + 4096);
    __syncthreads();   // drains vmcnt before any wave reads LDS

    bf16x8 af[4], bfr[4];
#pragma unroll
    for (int m = 0; m < 4; ++m)
      af[m] = *(const bf16x8*)(a_sh + a_rd + m * (16 * 32));
#pragma unroll
    for (int n = 0; n < 4; ++n)
      bfr[n] = *(const bf16x8*)(b_sh + b_rd + n * (16 * 32));
#pragma unroll
    for (int m = 0; m < 4; ++m)
#pragma unroll
      for (int n = 0; n < 4; ++n)
        acc[m][n] = __builtin_amdgcn_mfma_f32_16x16x32_bf16(af[m], bfr[n], acc[m][n], 0, 0, 0);
    __syncthreads();   // compute done before next stage overwrites LDS
  }

  // epilogue: C/D layout col = lane&15, row = (lane>>4)*4 + reg
  const int row0 = tm * 128 + wr * 64 + kq * 4;
  const int col0 = tn * 128 + wc * 64 + r16;
#pragma unroll
  for (int n = 0; n < 4; ++n) {
    const int col = col0 + n * 16;
    const float bv = bias[col];
#pragma unroll
    for (int m = 0; m < 4; ++m) {
      const int row = row0 + m * 16;
#pragma unroll
      for (int i = 0; i < 4; ++i)
        C[(size_t)(row + i) * GN + col] = acc[m][n][i] + bv;
    }
  }
}

// ---------------------------------------------------------------------------
extern "C" void kernel_launch(void* const* d_in, const int* in_sizes, int n_in,
                              void* d_out, int out_size, void* d_ws, size_t ws_size,
                              hipStream_t stream) {
  const float* Q  = (const float*)d_in[0];
  const float* K  = (const float*)d_in[1];
  const float* V  = (const float*)d_in[2];
  const float* Wq = (const float*)d_in[3];
  const float* bq = (const float*)d_in[4];
  const float* Wk = (const float*)d_in[5];
  const float* bk = (const float*)d_in[6];
  const float* Wv = (const float*)d_in[7];
  const float* bv = (const float*)d_in[8];
  const float* Wo = (const float*)d_in[9];
  const float* bo = (const float*)d_in[10];
  float* out = (float*)d_out;

  // ws layout: [WoT bf16 4096*4096][Oc bf16 3328*4096]
  __hip_bfloat16* WoT = (__hip_bfloat16*)d_ws;
  __hip_bfloat16* Oc  = (__hip_bfloat16*)((char*)d_ws + (size_t)GN * GK * 2);

  wo_transpose_kernel<<<dim3(64, 64), 256, 0, stream>>>(Wo, WoT);
  attn_kernel<<<dim3(H_SZ, B_SZ), 512, 0, stream>>>(Q, K, V, Wq, bq, Wk, bk, Wv, bv, Oc);
  out_gemm_kernel<<<dim3(26 * 32), 256, 0, stream>>>(Oc, WoT, bo, out);
}

// Round 2
// 248.696 us; speedup vs baseline: 3.4949x; 3.4949x over previous
//
#include <hip/hip_runtime.h>
#include <hip/hip_bf16.h>

// Problem constants
#define B_SZ   64
#define L_SZ   52
#define DMODEL 4096
#define H_SZ   32
#define C_SZ   128   // NEW_C = DMODEL/H
#define DK     128   // D_K == D_V

// Output GEMM dims: (B*L) x DMODEL = 3328 x 4096, K = 4096
#define GM 3328
#define GN 4096
#define GK 4096

typedef __bf16 bf16x8 __attribute__((ext_vector_type(8)));
typedef float  f32x4  __attribute__((ext_vector_type(4)));

__device__ __forceinline__ void gload_lds16(const void* g, void* l) {
  __builtin_amdgcn_global_load_lds(
      (__attribute__((address_space(1))) void*)(void*)g,
      (__attribute__((address_space(3))) void*)l, 16, 0, 0);
}

// ---------------------------------------------------------------------------
// Kernel 1a: Wo (4096x4096 fp32 [m][n]) -> WoT (4096x4096 bf16 [n][m])
// ---------------------------------------------------------------------------
__global__ __launch_bounds__(256) void wo_transpose_kernel(
    const float* __restrict__ Wo, __hip_bfloat16* __restrict__ WoT) {
  __shared__ float tile[64][65];
  const int nt = blockIdx.x, mt = blockIdx.y;
  const int t = threadIdx.x;
  const int r  = t >> 4;
  const int c4 = (t & 15) << 2;
#pragma unroll
  for (int p = 0; p < 4; ++p) {
    const int rr = r + p * 16;
    const float4 v = *(const float4*)(Wo + (size_t)(mt * 64 + rr) * 4096 + nt * 64 + c4);
    tile[rr][c4 + 0] = v.x; tile[rr][c4 + 1] = v.y;
    tile[rr][c4 + 2] = v.z; tile[rr][c4 + 3] = v.w;
  }
  __syncthreads();
#pragma unroll
  for (int p = 0; p < 4; ++p) {
    const int rr = r + p * 16;
    union { __hip_bfloat16 h[4]; ushort4 u; } o4;
#pragma unroll
    for (int e = 0; e < 4; ++e) o4.h[e] = __float2bfloat16(tile[c4 + e][rr]);
    *(ushort4*)(WoT + (size_t)(nt * 64 + rr) * 4096 + mt * 64 + c4) = o4.u;
  }
}

// ---------------------------------------------------------------------------
// Kernel 1b: Wq/Wk/Wv [h][c][k] fp32 -> [h][k][c] bf16   (batched 128x128 T)
// ---------------------------------------------------------------------------
__global__ __launch_bounds__(256) void w3_transpose_kernel(
    const float* __restrict__ Wq, const float* __restrict__ Wk,
    const float* __restrict__ Wv, __hip_bfloat16* __restrict__ WqT,
    __hip_bfloat16* __restrict__ WkT, __hip_bfloat16* __restrict__ WvT) {
  __shared__ float tile[64][65];
  const int bz = blockIdx.z;
  const float* in = (bz < 32 ? Wq : (bz < 64 ? Wk : Wv)) + (size_t)(bz & 31) * 16384;
  __hip_bfloat16* out = (bz < 32 ? WqT : (bz < 64 ? WkT : WvT)) + (size_t)(bz & 31) * 16384;
  const int nt = blockIdx.x, mt = blockIdx.y;  // 0..1
  const int t = threadIdx.x;
  const int r  = t >> 4;
  const int c4 = (t & 15) << 2;
#pragma unroll
  for (int p = 0; p < 4; ++p) {
    const int rr = r + p * 16;
    const float4 v = *(const float4*)(in + (size_t)(mt * 64 + rr) * 128 + nt * 64 + c4);
    tile[rr][c4 + 0] = v.x; tile[rr][c4 + 1] = v.y;
    tile[rr][c4 + 2] = v.z; tile[rr][c4 + 3] = v.w;
  }
  __syncthreads();
#pragma unroll
  for (int p = 0; p < 4; ++p) {
    const int rr = r + p * 16;
    union { __hip_bfloat16 h[4]; ushort4 u; } o4;
#pragma unroll
    for (int e = 0; e < 4; ++e) o4.h[e] = __float2bfloat16(tile[c4 + e][rr]);
    *(ushort4*)(out + (size_t)(nt * 64 + rr) * 128 + mt * 64 + c4) = o4.u;
  }
}

// ---------------------------------------------------------------------------
// Kernel 2: per-(b,h) MFMA attention. 256 threads = 4 waves.
// LDS regions (byte offsets), phase-overlaid:
//   r0 [    0,17408): xs_q  -> k_sh   (64x136 bf16)
//   r1 [17408,34816): xs_k  -> s_sh   (64x68 f32)
//   r2 [34816,52224): xs_v  -> q_sh -> p_sh (64x72 bf16)
//   r3 [52224,70656): vT             (128x72 bf16)
// Strides 136/72/68 chosen: 16B-aligned rows, 2-way (free) bank aliasing.
// ---------------------------------------------------------------------------
template <bool TRANSPOSED>
__device__ __forceinline__ void wave_proj(
    const __hip_bfloat16* __restrict__ xs, const __hip_bfloat16* __restrict__ WT,
    const float* __restrict__ bias, __hip_bfloat16* __restrict__ out,
    int n0, int r16, int kq) {
  f32x4 acc[4][2] = {};
  bf16x8 bfrag[2][4];
#pragma unroll
  for (int nt = 0; nt < 2; ++nt)
#pragma unroll
    for (int kk = 0; kk < 4; ++kk)
      bfrag[nt][kk] = *(const bf16x8*)(WT + (n0 + nt * 16 + r16) * 128 + kk * 32 + kq * 8);
#pragma unroll
  for (int kk = 0; kk < 4; ++kk) {
    bf16x8 a[4];
#pragma unroll
    for (int mt = 0; mt < 4; ++mt)
      a[mt] = *(const bf16x8*)(xs + (mt * 16 + r16) * 136 + kk * 32 + kq * 8);
#pragma unroll
    for (int mt = 0; mt < 4; ++mt)
#pragma unroll
      for (int nt = 0; nt < 2; ++nt)
        acc[mt][nt] = __builtin_amdgcn_mfma_f32_16x16x32_bf16(a[mt], bfrag[nt][kk], acc[mt][nt], 0, 0, 0);
  }
#pragma unroll
  for (int nt = 0; nt < 2; ++nt) {
    const int col = n0 + nt * 16 + r16;
    const float bv = bias[col];
#pragma unroll
    for (int mt = 0; mt < 4; ++mt) {
      const int m0 = mt * 16 + kq * 4;
      if (!TRANSPOSED) {
#pragma unroll
        for (int i = 0; i < 4; ++i)
          out[(m0 + i) * 136 + col] = __float2bfloat16(acc[mt][nt][i] + bv);
      } else {
        union { __hip_bfloat16 h[4]; ushort4 u; } o4;
        if (m0 < 52) {
#pragma unroll
          for (int i = 0; i < 4; ++i) o4.h[i] = __float2bfloat16(acc[mt][nt][i] + bv);
        } else {
          o4.u = make_ushort4(0, 0, 0, 0);   // pad keys: v rows 52..63 = 0
        }
        *(ushort4*)(out + col * 72 + m0) = o4.u;
      }
    }
  }
}

__global__ __launch_bounds__(256, 2) void attn_kernel(
    const float* __restrict__ Qin, const float* __restrict__ Kin,
    const float* __restrict__ Vin,
    const __hip_bfloat16* __restrict__ WqT, const float* __restrict__ bq,
    const __hip_bfloat16* __restrict__ WkT, const float* __restrict__ bk,
    const __hip_bfloat16* __restrict__ WvT, const float* __restrict__ bv,
    __hip_bfloat16* __restrict__ Oc) {
  __shared__ __align__(16) char lds[70656];
  __hip_bfloat16* xs0  = (__hip_bfloat16*)(lds);           // xs_q
  __hip_bfloat16* xs1  = (__hip_bfloat16*)(lds + 17408);   // xs_k
  __hip_bfloat16* xs2  = (__hip_bfloat16*)(lds + 34816);   // xs_v
  __hip_bfloat16* vT   = (__hip_bfloat16*)(lds + 52224);
  __hip_bfloat16* q_sh = (__hip_bfloat16*)(lds + 34816);
  __hip_bfloat16* k_sh = (__hip_bfloat16*)(lds);
  float*          s_sh = (float*)(lds + 17408);
  __hip_bfloat16* p_sh = (__hip_bfloat16*)(lds + 34816);

  const int h = blockIdx.x, bb = blockIdx.y;
  const int t = threadIdx.x;
  const int w = t >> 6, lane = t & 63;
  const int r16 = lane & 15, kq = lane >> 4;
  const size_t xoff = (size_t)bb * (L_SZ * DMODEL) + (size_t)h * (L_SZ * C_SZ);

  // ---- stage X (fp32 -> bf16, stride 136; zero pad rows 52..63) ----
  {
    const float* xp[3] = {Qin + xoff, Kin + xoff, Vin + xoff};
    __hip_bfloat16* xd[3] = {xs0, xs1, xs2};
#pragma unroll
    for (int tz = 0; tz < 3; ++tz) {
      const float* X = xp[tz];
      __hip_bfloat16* xs = xd[tz];
      for (int idx = t; idx < 52 * 32; idx += 256) {
        const int row = idx >> 5, c4 = (idx & 31) << 2;
        const float4 v = *(const float4*)(X + row * 128 + c4);
        union { __hip_bfloat16 h[4]; ushort4 u; } o4;
        o4.h[0] = __float2bfloat16(v.x); o4.h[1] = __float2bfloat16(v.y);
        o4.h[2] = __float2bfloat16(v.z); o4.h[3] = __float2bfloat16(v.w);
        *(ushort4*)(xs + row * 136 + c4) = o4.u;
      }
      if (t < 12 * 17) {
        const int row = 52 + t / 17, c8 = (t % 17) * 8;
        *(uint4*)(xs + row * 136 + c8) = make_uint4(0, 0, 0, 0);
      }
    }
  }
  __syncthreads();

  // ---- v-proj: xs2 -> vT (transposed, pad-zeroed) ----
  wave_proj<true>(xs2, WvT + (size_t)h * 16384, bv + h * 128, vT, w * 32, r16, kq);
  __syncthreads();
  // ---- q-proj: xs0 -> q_sh (overlays xs2) ----
  wave_proj<false>(xs0, WqT + (size_t)h * 16384, bq + h * 128, q_sh, w * 32, r16, kq);
  __syncthreads();
  // ---- k-proj: xs1 -> k_sh (overlays xs0) ----
  wave_proj<false>(xs1, WkT + (size_t)h * 16384, bk + h * 128, k_sh, w * 32, r16, kq);
  __syncthreads();

  // ---- QK^T -> s_sh (overlays xs1), scaled ----
  {
    const int n0 = w * 16;
    f32x4 sacc[4] = {};
#pragma unroll
    for (int kk = 0; kk < 4; ++kk) {
      const bf16x8 bf_ = *(const bf16x8*)(k_sh + (n0 + r16) * 136 + kk * 32 + kq * 8);
#pragma unroll
      for (int mt = 0; mt < 4; ++mt) {
        const bf16x8 a = *(const bf16x8*)(q_sh + (mt * 16 + r16) * 136 + kk * 32 + kq * 8);
        sacc[mt] = __builtin_amdgcn_mfma_f32_16x16x32_bf16(a, bf_, sacc[mt], 0, 0, 0);
      }
    }
    const float scale = 0.08838834764831845f;  // 1/sqrt(128)
#pragma unroll
    for (int mt = 0; mt < 4; ++mt)
#pragma unroll
      for (int i = 0; i < 4; ++i)
        s_sh[(mt * 16 + kq * 4 + i) * 68 + n0 + r16] = sacc[mt][i] * scale;
  }
  __syncthreads();

  // ---- masked softmax: s_sh -> p_sh (bf16, overlays q_sh) ----
  {
    const int r = t >> 2, qd = t & 3;   // 4 lanes per row, 16 cols each
    if (r < 52) {
      float v[16];
      float mx = -3e38f;
#pragma unroll
      for (int j4 = 0; j4 < 4; ++j4) {
        const f32x4 s4 = *(const f32x4*)(s_sh + r * 68 + qd * 16 + j4 * 4);
#pragma unroll
        for (int e = 0; e < 4; ++e) {
          const int col = qd * 16 + j4 * 4 + e;
          const float val = (col <= r) ? s4[e] : -3e38f;
          v[j4 * 4 + e] = val;
          mx = fmaxf(mx, val);
        }
      }
      mx = fmaxf(mx, __shfl_xor(mx, 1));
      mx = fmaxf(mx, __shfl_xor(mx, 2));
      float ex[16];
      float sum = 0.f;
#pragma unroll
      for (int j = 0; j < 16; ++j) {
        const int col = qd * 16 + j;
        const float e = (col <= r) ? __expf(v[j] - mx) : 0.f;
        ex[j] = e; sum += e;
      }
      sum += __shfl_xor(sum, 1);
      sum += __shfl_xor(sum, 2);
      const float inv = 1.0f / sum;
      union { __hip_bfloat16 h[8]; uint4 q; } p0, p1;
#pragma unroll
      for (int j = 0; j < 8; ++j) {
        p0.h[j] = __float2bfloat16(ex[j] * inv);
        p1.h[j] = __float2bfloat16(ex[8 + j] * inv);
      }
      *(uint4*)(p_sh + r * 72 + qd * 16)     = p0.q;
      *(uint4*)(p_sh + r * 72 + qd * 16 + 8) = p1.q;
    } else {
      *(uint4*)(p_sh + r * 72 + qd * 16)     = make_uint4(0, 0, 0, 0);
      *(uint4*)(p_sh + r * 72 + qd * 16 + 8) = make_uint4(0, 0, 0, 0);
    }
  }
  __syncthreads();

  // ---- PV: p_sh(64x64) @ v(64x128) -> Oc bf16 ----
  {
    const int n0 = w * 32;
    f32x4 oacc[4][2] = {};
#pragma unroll
    for (int kk = 0; kk < 2; ++kk) {
      bf16x8 bfr[2];
#pragma unroll
      for (int nt = 0; nt < 2; ++nt)
        bfr[nt] = *(const bf16x8*)(vT + (n0 + nt * 16 + r16) * 72 + kk * 32 + kq * 8);
#pragma unroll
      for (int mt = 0; mt < 4; ++mt) {
        const bf16x8 a = *(const bf16x8*)(p_sh + (mt * 16 + r16) * 72 + kk * 32 + kq * 8);
#pragma unroll
        for (int nt = 0; nt < 2; ++nt)
          oacc[mt][nt] = __builtin_amdgcn_mfma_f32_16x16x32_bf16(a, bfr[nt], oacc[mt][nt], 0, 0, 0);
      }
    }
    const size_t obase = (size_t)bb * 52 * 4096 + (size_t)h * 128;
#pragma unroll
    for (int nt = 0; nt < 2; ++nt) {
      const int col = n0 + nt * 16 + r16;
#pragma unroll
      for (int mt = 0; mt < 4; ++mt) {
        const int row0 = mt * 16 + kq * 4;
#pragma unroll
        for (int i = 0; i < 4; ++i) {
          const int row = row0 + i;
          if (row < 52)
            Oc[obase + (size_t)row * 4096 + col] = __float2bfloat16(oacc[mt][nt][i]);
        }
      }
    }
  }
}

// ---------------------------------------------------------------------------
// Kernel 3: C(3328x4096) = Oc @ WoT^T + bo   (m97 structure, unchanged)
// ---------------------------------------------------------------------------
__global__ __launch_bounds__(256, 2) void out_gemm_kernel(
    const __hip_bfloat16* __restrict__ A, const __hip_bfloat16* __restrict__ Bt,
    const float* __restrict__ bias, float* __restrict__ C) {
  __shared__ __align__(16) __hip_bfloat16 a_sh[128 * 32];
  __shared__ __align__(16) __hip_bfloat16 b_sh[128 * 32];

  int bid = blockIdx.x;
  bid = (bid & 7) * (26 * 32 / 8) + (bid >> 3);
  const int tm = bid >> 5;
  const int tn = bid & 31;

  const int t = threadIdx.x;
  const int lane = t & 63;
  const int w = t >> 6, wr = w >> 1, wc = w & 1;
  const int r16 = lane & 15, kq = lane >> 4;

  f32x4 acc[4][4] = {};

  const __hip_bfloat16* ga = A  + (size_t)(tm * 128 + (t >> 2)) * GK + (t & 3) * 8;
  const __hip_bfloat16* gb = Bt + (size_t)(tn * 128 + (t >> 2)) * GK + (t & 3) * 8;
  char* la = (char*)a_sh + t * 16;
  char* lb = (char*)b_sh + t * 16;

  const int a_rd = (wr * 64 + r16) * 32 + kq * 8;
  const int b_rd = (wc * 64 + r16) * 32 + kq * 8;

  for (int k0 = 0; k0 < GK; k0 += 32) {
    gload_lds16(ga + k0,                   la);
    gload_lds16(ga + (size_t)64 * GK + k0, la + 4096);
    gload_lds16(gb + k0,                   lb);
    gload_lds16(gb + (size_t)64 * GK + k0, lb + 4096);
    __syncthreads();

    bf16x8 af[4], bfr[4];
#pragma unroll
    for (int m = 0; m < 4; ++m)
      af[m] = *(const bf16x8*)(a_sh + a_rd + m * (16 * 32));
#pragma unroll
    for (int n = 0; n < 4; ++n)
      bfr[n] = *(const bf16x8*)(b_sh + b_rd + n * (16 * 32));
#pragma unroll
    for (int m = 0; m < 4; ++m)
#pragma unroll
      for (int n = 0; n < 4; ++n)
        acc[m][n] = __builtin_amdgcn_mfma_f32_16x16x32_bf16(af[m], bfr[n], acc[m][n], 0, 0, 0);
    __syncthreads();
  }

  const int row0 = tm * 128 + wr * 64 + kq * 4;
  const int col0 = tn * 128 + wc * 64 + r16;
#pragma unroll
  for (int n = 0; n < 4; ++n) {
    const int col = col0 + n * 16;
    const float bv = bias[col];
#pragma unroll
    for (int m = 0; m < 4; ++m) {
      const int row = row0 + m * 16;
#pragma unroll
      for (int i = 0; i < 4; ++i)
        C[(size_t)(row + i) * GN + col] = acc[m][n][i] + bv;
    }
  }
}

// ---------------------------------------------------------------------------
extern "C" void kernel_launch(void* const* d_in, const int* in_sizes, int n_in,
                              void* d_out, int out_size, void* d_ws, size_t ws_size,
                              hipStream_t stream) {
  const float* Q  = (const float*)d_in[0];
  const float* K  = (const float*)d_in[1];
  const float* V  = (const float*)d_in[2];
  const float* Wq = (const float*)d_in[3];
  const float* bq = (const float*)d_in[4];
  const float* Wk = (const float*)d_in[5];
  const float* bk = (const float*)d_in[6];
  const float* Wv = (const float*)d_in[7];
  const float* bv = (const float*)d_in[8];
  const float* Wo = (const float*)d_in[9];
  const float* bo = (const float*)d_in[10];
  float* out = (float*)d_out;

  // ws layout: [WoT bf16 32MB][Oc bf16 26MB][WqT|WkT|WvT bf16 1MB each]
  char* wsb = (char*)d_ws;
  __hip_bfloat16* WoT = (__hip_bfloat16*)wsb;
  __hip_bfloat16* Oc  = (__hip_bfloat16*)(wsb + (size_t)GN * GK * 2);
  __hip_bfloat16* WqT = (__hip_bfloat16*)(wsb + (size_t)GN * GK * 2 + (size_t)GM * GN * 2);
  __hip_bfloat16* WkT = WqT + (size_t)H_SZ * C_SZ * DK;
  __hip_bfloat16* WvT = WkT + (size_t)H_SZ * C_SZ * DK;

  w3_transpose_kernel<<<dim3(2, 2, 96), 256, 0, stream>>>(Wq, Wk, Wv, WqT, WkT, WvT);
  wo_transpose_kernel<<<dim3(64, 64), 256, 0, stream>>>(Wo, WoT);
  attn_kernel<<<dim3(H_SZ, B_SZ), 256, 0, stream>>>(Q, K, V, WqT, bq, WkT, bk, WvT, bv, Oc);
  out_gemm_kernel<<<dim3(26 * 32), 256, 0, stream>>>(Oc, WoT, bo, out);
}

// Round 3
// 220.083 us; speedup vs baseline: 3.9492x; 1.1300x over previous
//
#include <hip/hip_runtime.h>
#include <hip/hip_bf16.h>

// Problem constants
#define B_SZ   64
#define L_SZ   52
#define DMODEL 4096
#define H_SZ   32
#define C_SZ   128   // NEW_C = DMODEL/H
#define DK     128   // D_K == D_V

// Output GEMM dims: (B*L) x DMODEL = 3328 x 4096, K = 4096
#define GM 3328
#define GN 4096
#define GK 4096

typedef __bf16 bf16x8 __attribute__((ext_vector_type(8)));
typedef float  f32x4  __attribute__((ext_vector_type(4)));

__device__ __forceinline__ void gload_lds16(const void* g, void* l) {
  __builtin_amdgcn_global_load_lds(
      (__attribute__((address_space(1))) void*)(void*)g,
      (__attribute__((address_space(3))) void*)l, 16, 0, 0);
}

// ---------------------------------------------------------------------------
// Kernel 1a: Wo (4096x4096 fp32 [m][n]) -> WoT (4096x4096 bf16 [n][m])
// ---------------------------------------------------------------------------
__global__ __launch_bounds__(256) void wo_transpose_kernel(
    const float* __restrict__ Wo, __hip_bfloat16* __restrict__ WoT) {
  __shared__ float tile[64][65];
  const int nt = blockIdx.x, mt = blockIdx.y;
  const int t = threadIdx.x;
  const int r  = t >> 4;
  const int c4 = (t & 15) << 2;
#pragma unroll
  for (int p = 0; p < 4; ++p) {
    const int rr = r + p * 16;
    const float4 v = *(const float4*)(Wo + (size_t)(mt * 64 + rr) * 4096 + nt * 64 + c4);
    tile[rr][c4 + 0] = v.x; tile[rr][c4 + 1] = v.y;
    tile[rr][c4 + 2] = v.z; tile[rr][c4 + 3] = v.w;
  }
  __syncthreads();
#pragma unroll
  for (int p = 0; p < 4; ++p) {
    const int rr = r + p * 16;
    union { __hip_bfloat16 h[4]; ushort4 u; } o4;
#pragma unroll
    for (int e = 0; e < 4; ++e) o4.h[e] = __float2bfloat16(tile[c4 + e][rr]);
    *(ushort4*)(WoT + (size_t)(nt * 64 + rr) * 4096 + mt * 64 + c4) = o4.u;
  }
}

// ---------------------------------------------------------------------------
// Kernel 1b: Wq/Wk/Wv [h][c][k] fp32 -> [h][k][c] bf16   (batched 128x128 T)
// ---------------------------------------------------------------------------
__global__ __launch_bounds__(256) void w3_transpose_kernel(
    const float* __restrict__ Wq, const float* __restrict__ Wk,
    const float* __restrict__ Wv, __hip_bfloat16* __restrict__ WqT,
    __hip_bfloat16* __restrict__ WkT, __hip_bfloat16* __restrict__ WvT) {
  __shared__ float tile[64][65];
  const int bz = blockIdx.z;
  const float* in = (bz < 32 ? Wq : (bz < 64 ? Wk : Wv)) + (size_t)(bz & 31) * 16384;
  __hip_bfloat16* out = (bz < 32 ? WqT : (bz < 64 ? WkT : WvT)) + (size_t)(bz & 31) * 16384;
  const int nt = blockIdx.x, mt = blockIdx.y;  // 0..1
  const int t = threadIdx.x;
  const int r  = t >> 4;
  const int c4 = (t & 15) << 2;
#pragma unroll
  for (int p = 0; p < 4; ++p) {
    const int rr = r + p * 16;
    const float4 v = *(const float4*)(in + (size_t)(mt * 64 + rr) * 128 + nt * 64 + c4);
    tile[rr][c4 + 0] = v.x; tile[rr][c4 + 1] = v.y;
    tile[rr][c4 + 2] = v.z; tile[rr][c4 + 3] = v.w;
  }
  __syncthreads();
#pragma unroll
  for (int p = 0; p < 4; ++p) {
    const int rr = r + p * 16;
    union { __hip_bfloat16 h[4]; ushort4 u; } o4;
#pragma unroll
    for (int e = 0; e < 4; ++e) o4.h[e] = __float2bfloat16(tile[c4 + e][rr]);
    *(ushort4*)(out + (size_t)(nt * 64 + rr) * 128 + mt * 64 + c4) = o4.u;
  }
}

// ---------------------------------------------------------------------------
// Kernel 2: per-(b,h) MFMA attention. 256 threads = 4 waves. (unchanged)
// ---------------------------------------------------------------------------
template <bool TRANSPOSED>
__device__ __forceinline__ void wave_proj(
    const __hip_bfloat16* __restrict__ xs, const __hip_bfloat16* __restrict__ WT,
    const float* __restrict__ bias, __hip_bfloat16* __restrict__ out,
    int n0, int r16, int kq) {
  f32x4 acc[4][2] = {};
  bf16x8 bfrag[2][4];
#pragma unroll
  for (int nt = 0; nt < 2; ++nt)
#pragma unroll
    for (int kk = 0; kk < 4; ++kk)
      bfrag[nt][kk] = *(const bf16x8*)(WT + (n0 + nt * 16 + r16) * 128 + kk * 32 + kq * 8);
#pragma unroll
  for (int kk = 0; kk < 4; ++kk) {
    bf16x8 a[4];
#pragma unroll
    for (int mt = 0; mt < 4; ++mt)
      a[mt] = *(const bf16x8*)(xs + (mt * 16 + r16) * 136 + kk * 32 + kq * 8);
#pragma unroll
    for (int mt = 0; mt < 4; ++mt)
#pragma unroll
      for (int nt = 0; nt < 2; ++nt)
        acc[mt][nt] = __builtin_amdgcn_mfma_f32_16x16x32_bf16(a[mt], bfrag[nt][kk], acc[mt][nt], 0, 0, 0);
  }
#pragma unroll
  for (int nt = 0; nt < 2; ++nt) {
    const int col = n0 + nt * 16 + r16;
    const float bv = bias[col];
#pragma unroll
    for (int mt = 0; mt < 4; ++mt) {
      const int m0 = mt * 16 + kq * 4;
      if (!TRANSPOSED) {
#pragma unroll
        for (int i = 0; i < 4; ++i)
          out[(m0 + i) * 136 + col] = __float2bfloat16(acc[mt][nt][i] + bv);
      } else {
        union { __hip_bfloat16 h[4]; ushort4 u; } o4;
        if (m0 < 52) {
#pragma unroll
          for (int i = 0; i < 4; ++i) o4.h[i] = __float2bfloat16(acc[mt][nt][i] + bv);
        } else {
          o4.u = make_ushort4(0, 0, 0, 0);   // pad keys: v rows 52..63 = 0
        }
        *(ushort4*)(out + col * 72 + m0) = o4.u;
      }
    }
  }
}

__global__ __launch_bounds__(256, 2) void attn_kernel(
    const float* __restrict__ Qin, const float* __restrict__ Kin,
    const float* __restrict__ Vin,
    const __hip_bfloat16* __restrict__ WqT, const float* __restrict__ bq,
    const __hip_bfloat16* __restrict__ WkT, const float* __restrict__ bk,
    const __hip_bfloat16* __restrict__ WvT, const float* __restrict__ bv,
    __hip_bfloat16* __restrict__ Oc) {
  __shared__ __align__(16) char lds[70656];
  __hip_bfloat16* xs0  = (__hip_bfloat16*)(lds);
  __hip_bfloat16* xs1  = (__hip_bfloat16*)(lds + 17408);
  __hip_bfloat16* xs2  = (__hip_bfloat16*)(lds + 34816);
  __hip_bfloat16* vT   = (__hip_bfloat16*)(lds + 52224);
  __hip_bfloat16* q_sh = (__hip_bfloat16*)(lds + 34816);
  __hip_bfloat16* k_sh = (__hip_bfloat16*)(lds);
  float*          s_sh = (float*)(lds + 17408);
  __hip_bfloat16* p_sh = (__hip_bfloat16*)(lds + 34816);

  const int h = blockIdx.x, bb = blockIdx.y;
  const int t = threadIdx.x;
  const int w = t >> 6, lane = t & 63;
  const int r16 = lane & 15, kq = lane >> 4;
  const size_t xoff = (size_t)bb * (L_SZ * DMODEL) + (size_t)h * (L_SZ * C_SZ);

  {
    const float* xp[3] = {Qin + xoff, Kin + xoff, Vin + xoff};
    __hip_bfloat16* xd[3] = {xs0, xs1, xs2};
#pragma unroll
    for (int tz = 0; tz < 3; ++tz) {
      const float* X = xp[tz];
      __hip_bfloat16* xs = xd[tz];
      for (int idx = t; idx < 52 * 32; idx += 256) {
        const int row = idx >> 5, c4 = (idx & 31) << 2;
        const float4 v = *(const float4*)(X + row * 128 + c4);
        union { __hip_bfloat16 h[4]; ushort4 u; } o4;
        o4.h[0] = __float2bfloat16(v.x); o4.h[1] = __float2bfloat16(v.y);
        o4.h[2] = __float2bfloat16(v.z); o4.h[3] = __float2bfloat16(v.w);
        *(ushort4*)(xs + row * 136 + c4) = o4.u;
      }
      if (t < 12 * 17) {
        const int row = 52 + t / 17, c8 = (t % 17) * 8;
        *(uint4*)(xs + row * 136 + c8) = make_uint4(0, 0, 0, 0);
      }
    }
  }
  __syncthreads();

  wave_proj<true>(xs2, WvT + (size_t)h * 16384, bv + h * 128, vT, w * 32, r16, kq);
  __syncthreads();
  wave_proj<false>(xs0, WqT + (size_t)h * 16384, bq + h * 128, q_sh, w * 32, r16, kq);
  __syncthreads();
  wave_proj<false>(xs1, WkT + (size_t)h * 16384, bk + h * 128, k_sh, w * 32, r16, kq);
  __syncthreads();

  {
    const int n0 = w * 16;
    f32x4 sacc[4] = {};
#pragma unroll
    for (int kk = 0; kk < 4; ++kk) {
      const bf16x8 bf_ = *(const bf16x8*)(k_sh + (n0 + r16) * 136 + kk * 32 + kq * 8);
#pragma unroll
      for (int mt = 0; mt < 4; ++mt) {
        const bf16x8 a = *(const bf16x8*)(q_sh + (mt * 16 + r16) * 136 + kk * 32 + kq * 8);
        sacc[mt] = __builtin_amdgcn_mfma_f32_16x16x32_bf16(a, bf_, sacc[mt], 0, 0, 0);
      }
    }
    const float scale = 0.08838834764831845f;  // 1/sqrt(128)
#pragma unroll
    for (int mt = 0; mt < 4; ++mt)
#pragma unroll
      for (int i = 0; i < 4; ++i)
        s_sh[(mt * 16 + kq * 4 + i) * 68 + n0 + r16] = sacc[mt][i] * scale;
  }
  __syncthreads();

  {
    const int r = t >> 2, qd = t & 3;
    if (r < 52) {
      float v[16];
      float mx = -3e38f;
#pragma unroll
      for (int j4 = 0; j4 < 4; ++j4) {
        const f32x4 s4 = *(const f32x4*)(s_sh + r * 68 + qd * 16 + j4 * 4);
#pragma unroll
        for (int e = 0; e < 4; ++e) {
          const int col = qd * 16 + j4 * 4 + e;
          const float val = (col <= r) ? s4[e] : -3e38f;
          v[j4 * 4 + e] = val;
          mx = fmaxf(mx, val);
        }
      }
      mx = fmaxf(mx, __shfl_xor(mx, 1));
      mx = fmaxf(mx, __shfl_xor(mx, 2));
      float ex[16];
      float sum = 0.f;
#pragma unroll
      for (int j = 0; j < 16; ++j) {
        const int col = qd * 16 + j;
        const float e = (col <= r) ? __expf(v[j] - mx) : 0.f;
        ex[j] = e; sum += e;
      }
      sum += __shfl_xor(sum, 1);
      sum += __shfl_xor(sum, 2);
      const float inv = 1.0f / sum;
      union { __hip_bfloat16 h[8]; uint4 q; } p0, p1;
#pragma unroll
      for (int j = 0; j < 8; ++j) {
        p0.h[j] = __float2bfloat16(ex[j] * inv);
        p1.h[j] = __float2bfloat16(ex[8 + j] * inv);
      }
      *(uint4*)(p_sh + r * 72 + qd * 16)     = p0.q;
      *(uint4*)(p_sh + r * 72 + qd * 16 + 8) = p1.q;
    } else {
      *(uint4*)(p_sh + r * 72 + qd * 16)     = make_uint4(0, 0, 0, 0);
      *(uint4*)(p_sh + r * 72 + qd * 16 + 8) = make_uint4(0, 0, 0, 0);
    }
  }
  __syncthreads();

  {
    const int n0 = w * 32;
    f32x4 oacc[4][2] = {};
#pragma unroll
    for (int kk = 0; kk < 2; ++kk) {
      bf16x8 bfr[2];
#pragma unroll
      for (int nt = 0; nt < 2; ++nt)
        bfr[nt] = *(const bf16x8*)(vT + (n0 + nt * 16 + r16) * 72 + kk * 32 + kq * 8);
#pragma unroll
      for (int mt = 0; mt < 4; ++mt) {
        const bf16x8 a = *(const bf16x8*)(p_sh + (mt * 16 + r16) * 72 + kk * 32 + kq * 8);
#pragma unroll
        for (int nt = 0; nt < 2; ++nt)
          oacc[mt][nt] = __builtin_amdgcn_mfma_f32_16x16x32_bf16(a, bfr[nt], oacc[mt][nt], 0, 0, 0);
      }
    }
    const size_t obase = (size_t)bb * 52 * 4096 + (size_t)h * 128;
#pragma unroll
    for (int nt = 0; nt < 2; ++nt) {
      const int col = n0 + nt * 16 + r16;
#pragma unroll
      for (int mt = 0; mt < 4; ++mt) {
        const int row0 = mt * 16 + kq * 4;
#pragma unroll
        for (int i = 0; i < 4; ++i) {
          const int row = row0 + i;
          if (row < 52)
            Oc[obase + (size_t)row * 4096 + col] = __float2bfloat16(oacc[mt][nt][i]);
        }
      }
    }
  }
}

// ---------------------------------------------------------------------------
// Kernel 3: C(3328x4096) = Oc @ WoT^T + bo
// 256x256 tile, BK=32, 512 thr / 8 waves (2Mx4N), 4-deep LDS ring (128 KB),
// stage-lead 3 K-tiles, counted vmcnt(8) (never 0 in loop), one s_barrier
// per K-tile, setprio around MFMA cluster, XOR-swizzled LDS (2-way = free).
// Swizzle applied to global SOURCE on the write side (global_load_lds writes
// linearly) and to ds_read addresses on the read side (rule #21).
// ---------------------------------------------------------------------------
__global__ __launch_bounds__(512, 2) void out_gemm_kernel(
    const __hip_bfloat16* __restrict__ A, const __hip_bfloat16* __restrict__ Bt,
    const float* __restrict__ bias, float* __restrict__ C) {
  __shared__ __align__(16) char lds[131072];   // 4 bufs x (A 16K | B 16K)

  int bid = blockIdx.x;
  bid = (bid & 7) * 26 + (bid >> 3);     // XCD swizzle, 208 % 8 == 0 (bijective)
  const int tm = bid >> 4;               // 0..12
  const int tn = bid & 15;               // 0..15

  const int t = threadIdx.x;
  const int w = t >> 6, lane = t & 63;
  const int wm = w >> 2, wn = w & 3;
  const int r16 = lane & 15, kq = lane >> 4;

  // staging: wave w covers rows [w*32, w*32+32) of both A(m) and B(n) tiles;
  // 2 issues each (16 rows x 4 kblocks, lane -> row=lane>>2, kblock=lane&3).
  const int srow = (w << 5) + (lane >> 2);                  // 0..255
  const int sswz = ((lane & 3) ^ ((srow >> 1) & 3)) << 3;   // swizzled k-elem
  const char* gA = (const char*)(A  + (size_t)(tm * 256 + srow) * GK + sswz);
  const char* gB = (const char*)(Bt + (size_t)(tn * 256 + srow) * GK + sswz);
  const int dstA = (w << 11) + (lane << 4);                 // linear LDS dest
  const int dstB = 16384 + dstA;

  // read-side fragment offsets (byte), with matching XOR swizzle
  const int rswz = (kq ^ ((r16 >> 1) & 3)) << 4;
  const int cA = (wm << 13) + r16 * 64 + rswz;              // + mf*1024
  const int cB = 16384 + (wn << 12) + r16 * 64 + rswz;      // + nf*1024

  f32x4 acc[8][4] = {};

  // prologue: stage tiles 0,1,2 into bufs 0,1,2
#pragma unroll
  for (int pt = 0; pt < 3; ++pt) {
    char* db = lds + (pt << 15);
    const int sk = pt << 6;              // k byte offset (32 elems = 64 B)
    gload_lds16(gA + sk,          db + dstA);
    gload_lds16(gA + sk + 131072, db + dstA + 1024);   // +16 rows
    gload_lds16(gB + sk,          db + dstB);
    gload_lds16(gB + sk + 131072, db + dstB + 1024);
  }
  asm volatile("s_waitcnt vmcnt(8)" ::: "memory");   // tile 0 landed
  asm volatile("s_barrier" ::: "memory");

#pragma unroll 1
  for (int kt = 0; kt < 128; ++kt) {
    // stage tile kt+3 into buf (kt+3)&3 (that buffer's reads drained at kt-1)
    const int st = kt + 3;
    const int sk = (st < 128 ? st : 127) << 6;   // clamp tail: keep counts uniform
    char* db = lds + ((st & 3) << 15);
    gload_lds16(gA + sk,          db + dstA);
    gload_lds16(gA + sk + 131072, db + dstA + 1024);
    gload_lds16(gB + sk,          db + dstB);
    gload_lds16(gB + sk + 131072, db + dstB + 1024);

    // fragment reads for tile kt (landed: vmcnt(8)+barrier at kt-1)
    const char* rb = lds + ((kt & 3) << 15);
    bf16x8 af[8], bf_[4];
#pragma unroll
    for (int mf = 0; mf < 8; ++mf) af[mf] = *(const bf16x8*)(rb + cA + mf * 1024);
#pragma unroll
    for (int nf = 0; nf < 4; ++nf) bf_[nf] = *(const bf16x8*)(rb + cB + nf * 1024);

    __builtin_amdgcn_s_setprio(1);
#pragma unroll
    for (int mf = 0; mf < 8; ++mf)
#pragma unroll
      for (int nf = 0; nf < 4; ++nf)
        acc[mf][nf] = __builtin_amdgcn_mfma_f32_16x16x32_bf16(af[mf], bf_[nf], acc[mf][nf], 0, 0, 0);
    __builtin_amdgcn_s_setprio(0);

    // tile kt+1 (issued at kt-2) must land; leave tiles kt+2,kt+3 in flight
    asm volatile("s_waitcnt vmcnt(8)" ::: "memory");
    asm volatile("s_barrier" ::: "memory");
  }

  // epilogue: C/D layout col = lane&15, row = (lane>>4)*4 + reg
  const int row0 = tm * 256 + wm * 128 + kq * 4;
  const int col0 = tn * 256 + wn * 64 + r16;
#pragma unroll
  for (int nf = 0; nf < 4; ++nf) {
    const int col = col0 + nf * 16;
    const float bv = bias[col];
#pragma unroll
    for (int mf = 0; mf < 8; ++mf) {
      const int row = row0 + mf * 16;
#pragma unroll
      for (int i = 0; i < 4; ++i)
        C[(size_t)(row + i) * GN + col] = acc[mf][nf][i] + bv;
    }
  }
}

// ---------------------------------------------------------------------------
extern "C" void kernel_launch(void* const* d_in, const int* in_sizes, int n_in,
                              void* d_out, int out_size, void* d_ws, size_t ws_size,
                              hipStream_t stream) {
  const float* Q  = (const float*)d_in[0];
  const float* K  = (const float*)d_in[1];
  const float* V  = (const float*)d_in[2];
  const float* Wq = (const float*)d_in[3];
  const float* bq = (const float*)d_in[4];
  const float* Wk = (const float*)d_in[5];
  const float* bk = (const float*)d_in[6];
  const float* Wv = (const float*)d_in[7];
  const float* bv = (const float*)d_in[8];
  const float* Wo = (const float*)d_in[9];
  const float* bo = (const float*)d_in[10];
  float* out = (float*)d_out;

  char* wsb = (char*)d_ws;
  __hip_bfloat16* WoT = (__hip_bfloat16*)wsb;
  __hip_bfloat16* Oc  = (__hip_bfloat16*)(wsb + (size_t)GN * GK * 2);
  __hip_bfloat16* WqT = (__hip_bfloat16*)(wsb + (size_t)GN * GK * 2 + (size_t)GM * GN * 2);
  __hip_bfloat16* WkT = WqT + (size_t)H_SZ * C_SZ * DK;
  __hip_bfloat16* WvT = WkT + (size_t)H_SZ * C_SZ * DK;

  w3_transpose_kernel<<<dim3(2, 2, 96), 256, 0, stream>>>(Wq, Wk, Wv, WqT, WkT, WvT);
  wo_transpose_kernel<<<dim3(64, 64), 256, 0, stream>>>(Wo, WoT);
  attn_kernel<<<dim3(H_SZ, B_SZ), 256, 0, stream>>>(Q, K, V, WqT, bq, WkT, bk, WvT, bv, Oc);
  out_gemm_kernel<<<dim3(13 * 16), 512, 0, stream>>>(Oc, WoT, bo, out);
}

// Round 4
// 218.009 us; speedup vs baseline: 3.9868x; 1.0095x over previous
//
#include <hip/hip_runtime.h>
#include <hip/hip_bf16.h>

// Problem constants
#define B_SZ   64
#define L_SZ   52
#define DMODEL 4096
#define H_SZ   32
#define C_SZ   128   // NEW_C = DMODEL/H
#define DK     128   // D_K == D_V

// Output GEMM dims: (B*L) x DMODEL = 3328 x 4096, K = 4096
#define GM 3328
#define GN 4096
#define GK 4096

typedef __bf16 bf16x8 __attribute__((ext_vector_type(8)));
typedef float  f32x4  __attribute__((ext_vector_type(4)));

__device__ __forceinline__ void gload_lds16(const void* g, void* l) {
  __builtin_amdgcn_global_load_lds(
      (__attribute__((address_space(1))) void*)(void*)g,
      (__attribute__((address_space(3))) void*)l, 16, 0, 0);
}

// ---------------------------------------------------------------------------
// Kernel 1a: Wo (4096x4096 fp32 [m][n]) -> WoT (4096x4096 bf16 [n][m])
// ---------------------------------------------------------------------------
__global__ __launch_bounds__(256) void wo_transpose_kernel(
    const float* __restrict__ Wo, __hip_bfloat16* __restrict__ WoT) {
  __shared__ float tile[64][65];
  const int nt = blockIdx.x, mt = blockIdx.y;
  const int t = threadIdx.x;
  const int r  = t >> 4;
  const int c4 = (t & 15) << 2;
#pragma unroll
  for (int p = 0; p < 4; ++p) {
    const int rr = r + p * 16;
    const float4 v = *(const float4*)(Wo + (size_t)(mt * 64 + rr) * 4096 + nt * 64 + c4);
    tile[rr][c4 + 0] = v.x; tile[rr][c4 + 1] = v.y;
    tile[rr][c4 + 2] = v.z; tile[rr][c4 + 3] = v.w;
  }
  __syncthreads();
#pragma unroll
  for (int p = 0; p < 4; ++p) {
    const int rr = r + p * 16;
    union { __hip_bfloat16 h[4]; ushort4 u; } o4;
#pragma unroll
    for (int e = 0; e < 4; ++e) o4.h[e] = __float2bfloat16(tile[c4 + e][rr]);
    *(ushort4*)(WoT + (size_t)(nt * 64 + rr) * 4096 + mt * 64 + c4) = o4.u;
  }
}

// ---------------------------------------------------------------------------
// Kernel 1b: Wq/Wk/Wv [h][c][k] fp32 -> [h][k][c] bf16   (batched 128x128 T)
// ---------------------------------------------------------------------------
__global__ __launch_bounds__(256) void w3_transpose_kernel(
    const float* __restrict__ Wq, const float* __restrict__ Wk,
    const float* __restrict__ Wv, __hip_bfloat16* __restrict__ WqT,
    __hip_bfloat16* __restrict__ WkT, __hip_bfloat16* __restrict__ WvT) {
  __shared__ float tile[64][65];
  const int bz = blockIdx.z;
  const float* in = (bz < 32 ? Wq : (bz < 64 ? Wk : Wv)) + (size_t)(bz & 31) * 16384;
  __hip_bfloat16* out = (bz < 32 ? WqT : (bz < 64 ? WkT : WvT)) + (size_t)(bz & 31) * 16384;
  const int nt = blockIdx.x, mt = blockIdx.y;  // 0..1
  const int t = threadIdx.x;
  const int r  = t >> 4;
  const int c4 = (t & 15) << 2;
#pragma unroll
  for (int p = 0; p < 4; ++p) {
    const int rr = r + p * 16;
    const float4 v = *(const float4*)(in + (size_t)(mt * 64 + rr) * 128 + nt * 64 + c4);
    tile[rr][c4 + 0] = v.x; tile[rr][c4 + 1] = v.y;
    tile[rr][c4 + 2] = v.z; tile[rr][c4 + 3] = v.w;
  }
  __syncthreads();
#pragma unroll
  for (int p = 0; p < 4; ++p) {
    const int rr = r + p * 16;
    union { __hip_bfloat16 h[4]; ushort4 u; } o4;
#pragma unroll
    for (int e = 0; e < 4; ++e) o4.h[e] = __float2bfloat16(tile[c4 + e][rr]);
    *(ushort4*)(out + (size_t)(nt * 64 + rr) * 128 + mt * 64 + c4) = o4.u;
  }
}

// ---------------------------------------------------------------------------
// Kernel 2: per-(b,h) MFMA attention. 256 threads = 4 waves. (unchanged)
// ---------------------------------------------------------------------------
template <bool TRANSPOSED>
__device__ __forceinline__ void wave_proj(
    const __hip_bfloat16* __restrict__ xs, const __hip_bfloat16* __restrict__ WT,
    const float* __restrict__ bias, __hip_bfloat16* __restrict__ out,
    int n0, int r16, int kq) {
  f32x4 acc[4][2] = {};
  bf16x8 bfrag[2][4];
#pragma unroll
  for (int nt = 0; nt < 2; ++nt)
#pragma unroll
    for (int kk = 0; kk < 4; ++kk)
      bfrag[nt][kk] = *(const bf16x8*)(WT + (n0 + nt * 16 + r16) * 128 + kk * 32 + kq * 8);
#pragma unroll
  for (int kk = 0; kk < 4; ++kk) {
    bf16x8 a[4];
#pragma unroll
    for (int mt = 0; mt < 4; ++mt)
      a[mt] = *(const bf16x8*)(xs + (mt * 16 + r16) * 136 + kk * 32 + kq * 8);
#pragma unroll
    for (int mt = 0; mt < 4; ++mt)
#pragma unroll
      for (int nt = 0; nt < 2; ++nt)
        acc[mt][nt] = __builtin_amdgcn_mfma_f32_16x16x32_bf16(a[mt], bfrag[nt][kk], acc[mt][nt], 0, 0, 0);
  }
#pragma unroll
  for (int nt = 0; nt < 2; ++nt) {
    const int col = n0 + nt * 16 + r16;
    const float bv = bias[col];
#pragma unroll
    for (int mt = 0; mt < 4; ++mt) {
      const int m0 = mt * 16 + kq * 4;
      if (!TRANSPOSED) {
#pragma unroll
        for (int i = 0; i < 4; ++i)
          out[(m0 + i) * 136 + col] = __float2bfloat16(acc[mt][nt][i] + bv);
      } else {
        union { __hip_bfloat16 h[4]; ushort4 u; } o4;
        if (m0 < 52) {
#pragma unroll
          for (int i = 0; i < 4; ++i) o4.h[i] = __float2bfloat16(acc[mt][nt][i] + bv);
        } else {
          o4.u = make_ushort4(0, 0, 0, 0);   // pad keys: v rows 52..63 = 0
        }
        *(ushort4*)(out + col * 72 + m0) = o4.u;
      }
    }
  }
}

__global__ __launch_bounds__(256, 2) void attn_kernel(
    const float* __restrict__ Qin, const float* __restrict__ Kin,
    const float* __restrict__ Vin,
    const __hip_bfloat16* __restrict__ WqT, const float* __restrict__ bq,
    const __hip_bfloat16* __restrict__ WkT, const float* __restrict__ bk,
    const __hip_bfloat16* __restrict__ WvT, const float* __restrict__ bv,
    __hip_bfloat16* __restrict__ Oc) {
  __shared__ __align__(16) char lds[70656];
  __hip_bfloat16* xs0  = (__hip_bfloat16*)(lds);
  __hip_bfloat16* xs1  = (__hip_bfloat16*)(lds + 17408);
  __hip_bfloat16* xs2  = (__hip_bfloat16*)(lds + 34816);
  __hip_bfloat16* vT   = (__hip_bfloat16*)(lds + 52224);
  __hip_bfloat16* q_sh = (__hip_bfloat16*)(lds + 34816);
  __hip_bfloat16* k_sh = (__hip_bfloat16*)(lds);
  float*          s_sh = (float*)(lds + 17408);
  __hip_bfloat16* p_sh = (__hip_bfloat16*)(lds + 34816);

  const int h = blockIdx.x, bb = blockIdx.y;
  const int t = threadIdx.x;
  const int w = t >> 6, lane = t & 63;
  const int r16 = lane & 15, kq = lane >> 4;
  const size_t xoff = (size_t)bb * (L_SZ * DMODEL) + (size_t)h * (L_SZ * C_SZ);

  {
    const float* xp[3] = {Qin + xoff, Kin + xoff, Vin + xoff};
    __hip_bfloat16* xd[3] = {xs0, xs1, xs2};
#pragma unroll
    for (int tz = 0; tz < 3; ++tz) {
      const float* X = xp[tz];
      __hip_bfloat16* xs = xd[tz];
      for (int idx = t; idx < 52 * 32; idx += 256) {
        const int row = idx >> 5, c4 = (idx & 31) << 2;
        const float4 v = *(const float4*)(X + row * 128 + c4);
        union { __hip_bfloat16 h[4]; ushort4 u; } o4;
        o4.h[0] = __float2bfloat16(v.x); o4.h[1] = __float2bfloat16(v.y);
        o4.h[2] = __float2bfloat16(v.z); o4.h[3] = __float2bfloat16(v.w);
        *(ushort4*)(xs + row * 136 + c4) = o4.u;
      }
      if (t < 12 * 17) {
        const int row = 52 + t / 17, c8 = (t % 17) * 8;
        *(uint4*)(xs + row * 136 + c8) = make_uint4(0, 0, 0, 0);
      }
    }
  }
  __syncthreads();

  wave_proj<true>(xs2, WvT + (size_t)h * 16384, bv + h * 128, vT, w * 32, r16, kq);
  __syncthreads();
  wave_proj<false>(xs0, WqT + (size_t)h * 16384, bq + h * 128, q_sh, w * 32, r16, kq);
  __syncthreads();
  wave_proj<false>(xs1, WkT + (size_t)h * 16384, bk + h * 128, k_sh, w * 32, r16, kq);
  __syncthreads();

  {
    const int n0 = w * 16;
    f32x4 sacc[4] = {};
#pragma unroll
    for (int kk = 0; kk < 4; ++kk) {
      const bf16x8 bf_ = *(const bf16x8*)(k_sh + (n0 + r16) * 136 + kk * 32 + kq * 8);
#pragma unroll
      for (int mt = 0; mt < 4; ++mt) {
        const bf16x8 a = *(const bf16x8*)(q_sh + (mt * 16 + r16) * 136 + kk * 32 + kq * 8);
        sacc[mt] = __builtin_amdgcn_mfma_f32_16x16x32_bf16(a, bf_, sacc[mt], 0, 0, 0);
      }
    }
    const float scale = 0.08838834764831845f;  // 1/sqrt(128)
#pragma unroll
    for (int mt = 0; mt < 4; ++mt)
#pragma unroll
      for (int i = 0; i < 4; ++i)
        s_sh[(mt * 16 + kq * 4 + i) * 68 + n0 + r16] = sacc[mt][i] * scale;
  }
  __syncthreads();

  {
    const int r = t >> 2, qd = t & 3;
    if (r < 52) {
      float v[16];
      float mx = -3e38f;
#pragma unroll
      for (int j4 = 0; j4 < 4; ++j4) {
        const f32x4 s4 = *(const f32x4*)(s_sh + r * 68 + qd * 16 + j4 * 4);
#pragma unroll
        for (int e = 0; e < 4; ++e) {
          const int col = qd * 16 + j4 * 4 + e;
          const float val = (col <= r) ? s4[e] : -3e38f;
          v[j4 * 4 + e] = val;
          mx = fmaxf(mx, val);
        }
      }
      mx = fmaxf(mx, __shfl_xor(mx, 1));
      mx = fmaxf(mx, __shfl_xor(mx, 2));
      float ex[16];
      float sum = 0.f;
#pragma unroll
      for (int j = 0; j < 16; ++j) {
        const int col = qd * 16 + j;
        const float e = (col <= r) ? __expf(v[j] - mx) : 0.f;
        ex[j] = e; sum += e;
      }
      sum += __shfl_xor(sum, 1);
      sum += __shfl_xor(sum, 2);
      const float inv = 1.0f / sum;
      union { __hip_bfloat16 h[8]; uint4 q; } p0, p1;
#pragma unroll
      for (int j = 0; j < 8; ++j) {
        p0.h[j] = __float2bfloat16(ex[j] * inv);
        p1.h[j] = __float2bfloat16(ex[8 + j] * inv);
      }
      *(uint4*)(p_sh + r * 72 + qd * 16)     = p0.q;
      *(uint4*)(p_sh + r * 72 + qd * 16 + 8) = p1.q;
    } else {
      *(uint4*)(p_sh + r * 72 + qd * 16)     = make_uint4(0, 0, 0, 0);
      *(uint4*)(p_sh + r * 72 + qd * 16 + 8) = make_uint4(0, 0, 0, 0);
    }
  }
  __syncthreads();

  {
    const int n0 = w * 32;
    f32x4 oacc[4][2] = {};
#pragma unroll
    for (int kk = 0; kk < 2; ++kk) {
      bf16x8 bfr[2];
#pragma unroll
      for (int nt = 0; nt < 2; ++nt)
        bfr[nt] = *(const bf16x8*)(vT + (n0 + nt * 16 + r16) * 72 + kk * 32 + kq * 8);
#pragma unroll
      for (int mt = 0; mt < 4; ++mt) {
        const bf16x8 a = *(const bf16x8*)(p_sh + (mt * 16 + r16) * 72 + kk * 32 + kq * 8);
#pragma unroll
        for (int nt = 0; nt < 2; ++nt)
          oacc[mt][nt] = __builtin_amdgcn_mfma_f32_16x16x32_bf16(a, bfr[nt], oacc[mt][nt], 0, 0, 0);
      }
    }
    const size_t obase = (size_t)bb * 52 * 4096 + (size_t)h * 128;
#pragma unroll
    for (int nt = 0; nt < 2; ++nt) {
      const int col = n0 + nt * 16 + r16;
#pragma unroll
      for (int mt = 0; mt < 4; ++mt) {
        const int row0 = mt * 16 + kq * 4;
#pragma unroll
        for (int i = 0; i < 4; ++i) {
          const int row = row0 + i;
          if (row < 52)
            Oc[obase + (size_t)row * 4096 + col] = __float2bfloat16(oacc[mt][nt][i]);
        }
      }
    }
  }
}

// ---------------------------------------------------------------------------
// Kernel 3: C(3328x4096) = Oc @ WoT^T + bo  — 8-phase schedule (T2+T3+T4+T5)
// 256x256 tile, BK=64, 512 thr / 8 waves (2Mx4N), 2 LDS bufs of 64 KB.
// Buf layout: [Aks0 16K][Aks1 16K][Bks0 16K][Bks1 16K]; region = [256 rows] x
// [32 k] k-slice-major so each 16 KB region is contiguous (linear gload dest).
// Swizzle: LDS[row][slot] = global[row][slot ^ ((row>>1)&3)] (involution,
// rule #21: applied to global source AND ds_read address).
// Per K-tile: 4 phases (ks, mhalf): {ds_read 4-8, stage one region (2 gloads),
// barrier, lgkm0, setprio(1), 16 MFMA, setprio(0), barrier}. Stage stream in
// window T: [T+1.Aks1, T+1.Bks1, T+2.Aks0, T+2.Bks0] — every region staged
// only after its previous reads drained (ks0 regions die at phase u2).
// vmcnt(4) once per K-tile: only the last 2 staged regions may be in flight,
// and they are first read 4 phases later. Never vmcnt(0) in the loop.
// ---------------------------------------------------------------------------
#define STAGE(GBASE, REGOFF, KT, KS, WB) do {                                  \
    const __hip_bfloat16* s_ = (GBASE) + (size_t)(KT) * 64 + (KS) * 32;        \
    char* d_ = (WB) + (REGOFF) + ((KS) ? 16384 : 0) + t * 16;                  \
    gload_lds16(s_, d_);                                                       \
    gload_lds16(s_ + (size_t)128 * GK, d_ + 8192);                             \
  } while (0)

#define PHASE(KS, MH, STAGE_STMT, EXTRA_WAIT)                                  \
  {                                                                            \
    bf16x8 af[4];                                                              \
    _Pragma("unroll")                                                          \
    for (int mf = 0; mf < 4; ++mf)                                             \
      af[mf] = *(const bf16x8*)(rb + (KS) * 16384 + aBase + ((MH) * 4 + mf) * 1024); \
    if ((MH) == 0) {                                                           \
      _Pragma("unroll")                                                        \
      for (int nf = 0; nf < 4; ++nf)                                           \
        bf[nf] = *(const bf16x8*)(rb + 32768 + (KS) * 16384 + bBase + nf * 1024); \
    }                                                                          \
    STAGE_STMT;                                                                \
    __builtin_amdgcn_s_barrier();                                              \
    asm volatile("s_waitcnt lgkmcnt(0)" ::: "memory");                         \
    __builtin_amdgcn_sched_barrier(0);                                         \
    __builtin_amdgcn_s_setprio(1);                                             \
    _Pragma("unroll")                                                          \
    for (int mf = 0; mf < 4; ++mf)                                             \
      _Pragma("unroll")                                                        \
      for (int nf = 0; nf < 4; ++nf)                                           \
        acc[(MH) * 4 + mf][nf] = __builtin_amdgcn_mfma_f32_16x16x32_bf16(      \
            af[mf], bf[nf], acc[(MH) * 4 + mf][nf], 0, 0, 0);                  \
    __builtin_amdgcn_s_setprio(0);                                             \
    EXTRA_WAIT;                                                                \
    __builtin_amdgcn_s_barrier();                                              \
  }

__global__ __launch_bounds__(512, 2) void out_gemm_kernel(
    const __hip_bfloat16* __restrict__ A, const __hip_bfloat16* __restrict__ Bt,
    const float* __restrict__ bias, float* __restrict__ C) {
  __shared__ __align__(16) char lds[131072];   // 2 bufs x 64 KB

  int bid = blockIdx.x;
  bid = (bid & 7) * 26 + (bid >> 3);     // XCD swizzle, 208 % 8 == 0 (bijective)
  const int tm = bid >> 4;               // 0..12
  const int tn = bid & 15;               // 0..15

  const int t = threadIdx.x;
  const int w = t >> 6, lane = t & 63;
  const int wm = w >> 2, wn = w & 3;     // 2M x 4N waves; wave tile 128x64
  const int r16 = lane & 15, kq = lane >> 4;

  // staging geometry: thread t covers chunk q = t (+512 for round 1);
  // row = q>>2 (0..255), slot = q&3; global k-block = slot ^ ((row>>1)&3).
  const int srow = t >> 2;               // 0..127 (round 0)
  const int sgslot = (t & 3) ^ ((srow >> 1) & 3);
  const __hip_bfloat16* gA0 = A  + (size_t)(tm * 256 + srow) * GK + sgslot * 8;
  const __hip_bfloat16* gB0 = Bt + (size_t)(tn * 256 + srow) * GK + sgslot * 8;

  // read-side bases (byte): row*64 + (kq ^ ((r16>>1)&3))*16
  const int slotr = kq ^ ((r16 >> 1) & 3);
  const int aBase = (wm * 128 + r16) * 64 + slotr * 16;
  const int bBase = (wn * 64 + r16) * 64 + slotr * 16;

  f32x4 acc[8][4] = {};

  // prologue: tile0 (all 4 regions) -> buf0; tile1 ks0 (A,B) -> buf1
  STAGE(gA0, 0,     0, 0, lds);
  STAGE(gB0, 32768, 0, 0, lds);
  STAGE(gA0, 0,     0, 1, lds);
  STAGE(gB0, 32768, 0, 1, lds);
  STAGE(gA0, 0,     1, 0, lds + 65536);
  STAGE(gB0, 32768, 1, 0, lds + 65536);
  asm volatile("s_waitcnt vmcnt(4)" ::: "memory");   // tile0 fully landed
  __builtin_amdgcn_s_barrier();

#pragma unroll 1
  for (int kt = 0; kt < 64; ++kt) {
    const char* rb = lds + ((kt & 1) << 16);
    char* wb1 = lds + (((kt + 1) & 1) << 16);
    char* wb2 = (char*)rb;                  // (kt+2) has same parity as kt
    const int st1 = kt + 1 < 64 ? kt + 1 : 63;   // clamped tail sources
    const int st2 = kt + 2 < 64 ? kt + 2 : 63;
    bf16x8 bf[4];
    PHASE(0, 0, STAGE(gA0, 0,     st1, 1, wb1), )
    PHASE(0, 1, STAGE(gB0, 32768, st1, 1, wb1), )
    PHASE(1, 0, STAGE(gA0, 0,     st2, 0, wb2), )
    PHASE(1, 1, STAGE(gB0, 32768, st2, 0, wb2),
          asm volatile("s_waitcnt vmcnt(4)" ::: "memory"))
  }
  asm volatile("s_waitcnt vmcnt(0)" ::: "memory");   // drain before LDS retire

  // epilogue: C/D layout col = lane&15, row = (lane>>4)*4 + reg
  const int row0 = tm * 256 + wm * 128 + kq * 4;
  const int col0 = tn * 256 + wn * 64 + r16;
#pragma unroll
  for (int nf = 0; nf < 4; ++nf) {
    const int col = col0 + nf * 16;
    const float bv = bias[col];
#pragma unroll
    for (int mf = 0; mf < 8; ++mf) {
      const int row = row0 + mf * 16;
#pragma unroll
      for (int i = 0; i < 4; ++i)
        C[(size_t)(row + i) * GN + col] = acc[mf][nf][i] + bv;
    }
  }
}

// ---------------------------------------------------------------------------
extern "C" void kernel_launch(void* const* d_in, const int* in_sizes, int n_in,
                              void* d_out, int out_size, void* d_ws, size_t ws_size,
                              hipStream_t stream) {
  const float* Q  = (const float*)d_in[0];
  const float* K  = (const float*)d_in[1];
  const float* V  = (const float*)d_in[2];
  const float* Wq = (const float*)d_in[3];
  const float* bq = (const float*)d_in[4];
  const float* Wk = (const float*)d_in[5];
  const float* bk = (const float*)d_in[6];
  const float* Wv = (const float*)d_in[7];
  const float* bv = (const float*)d_in[8];
  const float* Wo = (const float*)d_in[9];
  const float* bo = (const float*)d_in[10];
  float* out = (float*)d_out;

  char* wsb = (char*)d_ws;
  __hip_bfloat16* WoT = (__hip_bfloat16*)wsb;
  __hip_bfloat16* Oc  = (__hip_bfloat16*)(wsb + (size_t)GN * GK * 2);
  __hip_bfloat16* WqT = (__hip_bfloat16*)(wsb + (size_t)GN * GK * 2 + (size_t)GM * GN * 2);
  __hip_bfloat16* WkT = WqT + (size_t)H_SZ * C_SZ * DK;
  __hip_bfloat16* WvT = WkT + (size_t)H_SZ * C_SZ * DK;

  w3_transpose_kernel<<<dim3(2, 2, 96), 256, 0, stream>>>(Wq, Wk, Wv, WqT, WkT, WvT);
  wo_transpose_kernel<<<dim3(64, 64), 256, 0, stream>>>(Wo, WoT);
  attn_kernel<<<dim3(H_SZ, B_SZ), 256, 0, stream>>>(Q, K, V, WqT, bq, WkT, bk, WvT, bv, Oc);
  out_gemm_kernel<<<dim3(13 * 16), 512, 0, stream>>>(Oc, WoT, bo, out);
}